// Round 3
// baseline (78.957 us; speedup 1.0000x reference)
//
#include <hip/hip_runtime.h>
#include <hip/hip_bf16.h>

#define NEG_BIG -1000000.0f

typedef __attribute__((ext_vector_type(8))) short short8;
typedef __attribute__((ext_vector_type(4))) float floatx4;

#if __has_builtin(__builtin_amdgcn_exp2f)
#define EXP2F(x) __builtin_amdgcn_exp2f(x)
#else
#define EXP2F(x) exp2f(x)
#endif

static __device__ __forceinline__ unsigned short bf16u(float f) {
    union { __hip_bfloat16 h; unsigned short u; } c;
    c.h = __float2bfloat16(f);
    return c.u;
}

static __device__ __forceinline__ short8 pack8(float4 a, float4 b) {
    union { short8 s; __hip_bfloat162 h[4]; } u;
    u.h[0] = __float22bfloat162_rn(make_float2(a.x, a.y));
    u.h[1] = __float22bfloat162_rn(make_float2(a.z, a.w));
    u.h[2] = __float22bfloat162_rn(make_float2(b.x, b.y));
    u.h[3] = __float22bfloat162_rn(make_float2(b.z, b.w));
    return u.s;
}

// Block: 256 thr = 4 waves, 64 q-rows (wave owns one 16-row tile).
// Grid: 1024 blocks, XCD-swizzled. KV tile = 64, double-buffered.
// LDS = 32 KB exactly (K dbuf + VT dbuf, XOR-swizzled, no pad) ->
// all 1024 blocks resident at 4 blocks/CU. P scratch aliases the
// K prefetch buffer's per-wave rows (staging is per-wave partitioned).
// Softmax runs in exp2 domain (log2e folded into Q pre-scale).
__global__ __launch_bounds__(256, 4)
void attn_fwd(const float* __restrict__ Q, const float* __restrict__ K,
              const float* __restrict__ V, const int* __restrict__ vlen,
              float* __restrict__ out)
{
    // K_lds: elem (row,col) at row*64 + (col ^ ((row&7)*8))
    __shared__ __attribute__((aligned(16))) unsigned short K_lds[2][4096];
    // VT_lds: elem (dv,k) at dv*64 + (k ^ (((dv&7) ^ (dv>>3)) * 8))
    __shared__ __attribute__((aligned(16))) unsigned short VT_lds[2][4096];

    const int bid  = blockIdx.x;
    const int orig = (bid & 7) * 128 + (bid >> 3);  // bijective (1024%8==0)
    const int b    = orig >> 4;
    const int qc   = orig & 15;

    const int tid = threadIdx.x;
    const int l   = tid & 63;
    const int w   = tid >> 6;
    const int lr  = l & 15;
    const int lg  = l >> 4;

    const float* Qb = Q + (size_t)b * 65536;
    const float* Kb = K + (size_t)b * 65536;
    const float* Vb = V + (size_t)b * 65536;
    float*       Ob = out + (size_t)b * 65536;

    const int valid = vlen[b];
    const int kmax  = (valid == 0) ? 1024 : valid;   // all-masked -> uniform
    const int ntile = (kmax + 63) >> 6;

    // Q fragments, pre-scaled by log2(e)/sqrt(64)
    const float qscale = 0.18033688011112042f;
    short8 qf[2];
#pragma unroll
    for (int c = 0; c < 2; ++c) {
        const float* p = Qb + (size_t)(qc*64 + w*16 + lr) * 64 + c*32 + lg*8;
        float4 a = *(const float4*)p, bb = *(const float4*)(p + 4);
        a.x *= qscale; a.y *= qscale; a.z *= qscale; a.w *= qscale;
        bb.x *= qscale; bb.y *= qscale; bb.z *= qscale; bb.w *= qscale;
        qf[c] = pack8(a, bb);
    }

    floatx4 o[4];
    float m[4], lsum[4];
#pragma unroll
    for (int n = 0; n < 4; ++n) o[n] = (floatx4){0.f, 0.f, 0.f, 0.f};
#pragma unroll
    for (int r = 0; r < 4; ++r) { m[r] = -INFINITY; lsum[r] = 0.f; }

    // per-wave staging: wave w stages tile rows [w*16, w*16+16)
    const int r_loc = l >> 2;            // 0..15
    const int row   = w * 16 + r_loc;    // 0..63 (tile row)
    const int q4    = l & 3;
    const int cbase = q4 * 16;           // col quarter

    float4 kra[4], vra[4];

#define LOAD_TILE(T) do {                                                   \
    const int _k0 = (T) * 64;                                               \
    const float* pk = Kb + (size_t)(_k0 + row) * 64 + cbase;                \
    kra[0] = *(const float4*)pk;     kra[1] = *(const float4*)(pk + 4);     \
    kra[2] = *(const float4*)(pk+8); kra[3] = *(const float4*)(pk + 12);    \
    const float* pv = Vb + (size_t)(_k0 + row) * 64 + cbase;                \
    vra[0] = *(const float4*)pv;     vra[1] = *(const float4*)(pv + 4);     \
    vra[2] = *(const float4*)(pv+8); vra[3] = *(const float4*)(pv + 12);    \
    } while (0)

#define WRITE_TILE(B) do {                                                  \
    const int _fk = (row & 7) * 8;                                          \
    *(short8*)&K_lds[B][row*64 + (cbase ^ _fk)]       = pack8(kra[0], kra[1]); \
    *(short8*)&K_lds[B][row*64 + ((cbase + 8) ^ _fk)] = pack8(kra[2], kra[3]); \
    _Pragma("unroll")                                                       \
    for (int j = 0; j < 16; ++j) {                                          \
        const int dv = cbase + j;                                           \
        const int fv = ((dv & 7) ^ (dv >> 3)) * 8;                          \
        VT_lds[B][dv*64 + (row ^ fv)] = bf16u(((const float*)&vra[j>>2])[j&3]); \
    } } while (0)

    LOAD_TILE(0);
    WRITE_TILE(0);
    __syncthreads();

    for (int t = 0; t < ntile; ++t) {
        const int cur = t & 1;
        const int nxt = cur ^ 1;
        const int k0  = t * 64;

        if (t + 1 < ntile) LOAD_TILE(t + 1);    // global loads in flight

        // ---- QK^T: S[16q x 64k]; lane holds q=lg*4+r, k=n*16+lr ----
        floatx4 sa[4];
#pragma unroll
        for (int n = 0; n < 4; ++n) {
            const int kr  = n*16 + lr;
            const int fk  = (lr & 7) * 8;
            const short8 kf0 = *(const short8*)&K_lds[cur][kr*64 + ((lg*8)      ^ fk)];
            const short8 kf1 = *(const short8*)&K_lds[cur][kr*64 + ((32 + lg*8) ^ fk)];
            sa[n] = (floatx4){0.f, 0.f, 0.f, 0.f};
            sa[n] = __builtin_amdgcn_mfma_f32_16x16x32_bf16(qf[0], kf0, sa[n], 0, 0, 0);
            sa[n] = __builtin_amdgcn_mfma_f32_16x16x32_bf16(qf[1], kf1, sa[n], 0, 0, 0);
        }

        if ((k0 + 64) > valid) {
#pragma unroll
            for (int n = 0; n < 4; ++n) {
                const bool msk = (k0 + n*16 + lr) >= valid;
#pragma unroll
                for (int r = 0; r < 4; ++r) sa[n][r] = msk ? NEG_BIG : sa[n][r];
            }
        }

        // ---- online softmax, exp2 domain ----
        float rmax[4];
#pragma unroll
        for (int r = 0; r < 4; ++r)
            rmax[r] = fmaxf(fmaxf(sa[0][r], sa[1][r]), fmaxf(sa[2][r], sa[3][r]));
#pragma unroll
        for (int off = 8; off >= 1; off >>= 1)
#pragma unroll
            for (int r = 0; r < 4; ++r)
                rmax[r] = fmaxf(rmax[r], __shfl_xor(rmax[r], off));
        float nm[4], sc[4];
#pragma unroll
        for (int r = 0; r < 4; ++r) {
            nm[r] = fmaxf(m[r], rmax[r]);
            sc[r] = EXP2F(m[r] - nm[r]);     // first tile: exp2(-inf)=0
            m[r]  = nm[r];
        }
        float rs[4] = {0.f, 0.f, 0.f, 0.f};
        float pp[4][4];
#pragma unroll
        for (int n = 0; n < 4; ++n)
#pragma unroll
        for (int r = 0; r < 4; ++r) {
            pp[n][r] = EXP2F(sa[n][r] - nm[r]);
            rs[r] += pp[n][r];
        }
#pragma unroll
        for (int off = 8; off >= 1; off >>= 1)
#pragma unroll
            for (int r = 0; r < 4; ++r)
                rs[r] += __shfl_xor(rs[r], off);
#pragma unroll
        for (int r = 0; r < 4; ++r) lsum[r] = lsum[r] * sc[r] + rs[r];
#pragma unroll
        for (int n = 0; n < 4; ++n)
#pragma unroll
        for (int r = 0; r < 4; ++r) o[n][r] *= sc[r];

        // ---- P via scratch aliased into K prefetch buffer (per-wave rows) ----
        // safe: K_lds[nxt] was last read before the previous barrier; only
        // wave w touches rows [w*16,w*16+16) (staging is per-wave partitioned);
        // wave's own K-write below follows its P-read in LDS program order.
#pragma unroll
        for (int n = 0; n < 4; ++n)
#pragma unroll
        for (int r = 0; r < 4; ++r) {
            const int prow = lg*4 + r;
            K_lds[nxt][(w*16 + prow)*64 + ((n*16 + lr) ^ ((prow & 7) * 8))] = bf16u(pp[n][r]);
        }
        const int fp = (lr & 7) * 8;
        const short8 pa0 = *(const short8*)&K_lds[nxt][(w*16 + lr)*64 + ((lg*8)      ^ fp)];
        const short8 pa1 = *(const short8*)&K_lds[nxt][(w*16 + lr)*64 + ((32 + lg*8) ^ fp)];

        // ---- PV ----
#pragma unroll
        for (int n = 0; n < 4; ++n) {
            const int dv  = n*16 + lr;
            const int fv0 = ((lr & 7) ^ (n*2 + (lr >> 3))) * 8;
            const short8 vf0 = *(const short8*)&VT_lds[cur][dv*64 + ((lg*8)      ^ fv0)];
            const short8 vf1 = *(const short8*)&VT_lds[cur][dv*64 + ((32 + lg*8) ^ fv0)];
            o[n] = __builtin_amdgcn_mfma_f32_16x16x32_bf16(pa0, vf0, o[n], 0, 0, 0);
            o[n] = __builtin_amdgcn_mfma_f32_16x16x32_bf16(pa1, vf1, o[n], 0, 0, 0);
        }

        if (t + 1 < ntile) WRITE_TILE(nxt);   // vmcnt wait lands here
        __syncthreads();                      // one barrier per tile
    }

    // ---- epilogue ----
    float inv[4];
#pragma unroll
    for (int r = 0; r < 4; ++r) inv[r] = 1.0f / lsum[r];
#pragma unroll
    for (int n = 0; n < 4; ++n)
#pragma unroll
    for (int r = 0; r < 4; ++r) {
        const int q = qc*64 + w*16 + lg*4 + r;
        Ob[(size_t)q * 64 + n*16 + lr] = o[n][r] * inv[r];
    }
#undef LOAD_TILE
#undef WRITE_TILE
}

extern "C" void kernel_launch(void* const* d_in, const int* in_sizes, int n_in,
                              void* d_out, int out_size, void* d_ws, size_t ws_size,
                              hipStream_t stream) {
    (void)in_sizes; (void)n_in; (void)d_ws; (void)ws_size; (void)out_size;
    const float* Q  = (const float*)d_in[0];
    const float* K  = (const float*)d_in[1];
    const float* V  = (const float*)d_in[2];
    const int*   vl = (const int*)d_in[3];
    float* O = (float*)d_out;
    attn_fwd<<<dim3(1024), dim3(256), 0, stream>>>(Q, K, V, vl, O);
}

// Round 4
// 76.161 us; speedup vs baseline: 1.0367x; 1.0367x over previous
//
#include <hip/hip_runtime.h>
#include <hip/hip_bf16.h>

#define NEG_BIG -1000000.0f

typedef __attribute__((ext_vector_type(8))) short short8;
typedef __attribute__((ext_vector_type(4))) float floatx4;

#if __has_builtin(__builtin_amdgcn_exp2f)
#define EXP2F(x) __builtin_amdgcn_exp2f(x)
#else
#define EXP2F(x) exp2f(x)
#endif

static __device__ __forceinline__ unsigned short bf16u(float f) {
    union { __hip_bfloat16 h; unsigned short u; } c;
    c.h = __float2bfloat16(f);
    return c.u;
}

static __device__ __forceinline__ short8 pack8(float4 a, float4 b) {
    union { short8 s; __hip_bfloat162 h[4]; } u;
    u.h[0] = __float22bfloat162_rn(make_float2(a.x, a.y));
    u.h[1] = __float22bfloat162_rn(make_float2(a.z, a.w));
    u.h[2] = __float22bfloat162_rn(make_float2(b.x, b.y));
    u.h[3] = __float22bfloat162_rn(make_float2(b.z, b.w));
    return u.s;
}

// Block: 256 thr = 4 waves, 64 q-rows (wave owns one 16-row tile).
// Grid: 1024 blocks, XCD-swizzled. KV tile = 64, double-buffered, 32 KB LDS.
// Register discipline (r3 spilled at the 128 unified-reg cap):
//   - K prefetch regs live only LOAD_K .. WRITE_K (through QK^T/softmax)
//   - V prefetch regs live only LOAD_V .. WRITE_V (through PV)
//   - sa[] reused in place as P (exp2 applied in place)
// P scratch aliases K prefetch buffer rows (per-wave partitioned; same-wave
// DS program order makes P-read -> K-write safe).
__global__ __launch_bounds__(256, 4)
void attn_fwd(const float* __restrict__ Q, const float* __restrict__ K,
              const float* __restrict__ V, const int* __restrict__ vlen,
              float* __restrict__ out)
{
    // K_lds: elem (row,col) at row*64 + (col ^ ((row&7)*8))
    __shared__ __attribute__((aligned(16))) unsigned short K_lds[2][4096];
    // VT_lds: elem (dv,k) at dv*64 + (k ^ (((dv&7) ^ (dv>>3)) * 8))
    __shared__ __attribute__((aligned(16))) unsigned short VT_lds[2][4096];

    const int bid  = blockIdx.x;
    const int orig = (bid & 7) * 128 + (bid >> 3);  // bijective (1024%8==0)
    const int b    = orig >> 4;
    const int qc   = orig & 15;

    const int tid = threadIdx.x;
    const int l   = tid & 63;
    const int w   = tid >> 6;
    const int lr  = l & 15;
    const int lg  = l >> 4;

    const float* Qb = Q + (size_t)b * 65536;
    const float* Kb = K + (size_t)b * 65536;
    const float* Vb = V + (size_t)b * 65536;
    float*       Ob = out + (size_t)b * 65536;

    const int valid = vlen[b];
    const int kmax  = (valid == 0) ? 1024 : valid;   // all-masked -> uniform
    const int ntile = (kmax + 63) >> 6;

    // Q fragments, pre-scaled by log2(e)/sqrt(64)
    const float qscale = 0.18033688011112042f;
    short8 qf[2];
#pragma unroll
    for (int c = 0; c < 2; ++c) {
        const float* p = Qb + (size_t)(qc*64 + w*16 + lr) * 64 + c*32 + lg*8;
        float4 a = *(const float4*)p, bb = *(const float4*)(p + 4);
        a.x *= qscale; a.y *= qscale; a.z *= qscale; a.w *= qscale;
        bb.x *= qscale; bb.y *= qscale; bb.z *= qscale; bb.w *= qscale;
        qf[c] = pack8(a, bb);
    }

    floatx4 o[4];
    float m[4], lsum[4];
#pragma unroll
    for (int n = 0; n < 4; ++n) o[n] = (floatx4){0.f, 0.f, 0.f, 0.f};
#pragma unroll
    for (int r = 0; r < 4; ++r) { m[r] = -INFINITY; lsum[r] = 0.f; }

    // per-wave staging: wave w stages tile rows [w*16, w*16+16)
    const int row   = w * 16 + (l >> 2);  // 0..63
    const int cbase = (l & 3) * 16;       // col quarter (floats)

    float4 kra[4], vra[4];

#define LOAD_K(T) do {                                                      \
    const float* pk = Kb + (size_t)((T)*64 + row) * 64 + cbase;             \
    kra[0] = *(const float4*)pk;       kra[1] = *(const float4*)(pk + 4);   \
    kra[2] = *(const float4*)(pk + 8); kra[3] = *(const float4*)(pk + 12);  \
    } while (0)

#define LOAD_V(T) do {                                                      \
    const float* pv = Vb + (size_t)((T)*64 + row) * 64 + cbase;             \
    vra[0] = *(const float4*)pv;       vra[1] = *(const float4*)(pv + 4);   \
    vra[2] = *(const float4*)(pv + 8); vra[3] = *(const float4*)(pv + 12);  \
    } while (0)

#define WRITE_K(B) do {                                                     \
    const int _fk = (row & 7) * 8;                                          \
    *(short8*)&K_lds[B][row*64 + (cbase ^ _fk)]       = pack8(kra[0], kra[1]); \
    *(short8*)&K_lds[B][row*64 + ((cbase + 8) ^ _fk)] = pack8(kra[2], kra[3]); \
    } while (0)

#define WRITE_V(B) do {                                                     \
    _Pragma("unroll")                                                       \
    for (int j = 0; j < 16; ++j) {                                          \
        const int dv = cbase + j;                                           \
        const int fv = ((dv & 7) ^ (dv >> 3)) * 8;                          \
        VT_lds[B][dv*64 + (row ^ fv)] = bf16u(((const float*)&vra[j>>2])[j&3]); \
    } } while (0)

    LOAD_K(0);
    LOAD_V(0);
    WRITE_K(0);
    WRITE_V(0);
    __syncthreads();

    for (int t = 0; t < ntile; ++t) {
        const int cur = t & 1;
        const int nxt = cur ^ 1;
        const int k0  = t * 64;
        const bool pf = (t + 1 < ntile);

        if (pf) LOAD_K(t + 1);   // in flight through QK^T + softmax

        // ---- QK^T: S[16q x 64k]; lane holds q=lg*4+r, k=n*16+lr ----
        floatx4 sa[4];
        __builtin_amdgcn_s_setprio(1);
#pragma unroll
        for (int n = 0; n < 4; ++n) {
            const int kr = n*16 + lr;
            const int fk = (lr & 7) * 8;
            const short8 kf0 = *(const short8*)&K_lds[cur][kr*64 + ((lg*8)      ^ fk)];
            const short8 kf1 = *(const short8*)&K_lds[cur][kr*64 + ((32 + lg*8) ^ fk)];
            sa[n] = (floatx4){0.f, 0.f, 0.f, 0.f};
            sa[n] = __builtin_amdgcn_mfma_f32_16x16x32_bf16(qf[0], kf0, sa[n], 0, 0, 0);
            sa[n] = __builtin_amdgcn_mfma_f32_16x16x32_bf16(qf[1], kf1, sa[n], 0, 0, 0);
        }
        __builtin_amdgcn_s_setprio(0);

        if ((k0 + 64) > valid) {
#pragma unroll
            for (int n = 0; n < 4; ++n) {
                const bool msk = (k0 + n*16 + lr) >= valid;
#pragma unroll
                for (int r = 0; r < 4; ++r) sa[n][r] = msk ? NEG_BIG : sa[n][r];
            }
        }

        // ---- online softmax, exp2 domain; sa becomes P in place ----
        float rmax[4];
#pragma unroll
        for (int r = 0; r < 4; ++r)
            rmax[r] = fmaxf(fmaxf(sa[0][r], sa[1][r]), fmaxf(sa[2][r], sa[3][r]));
#pragma unroll
        for (int off = 8; off >= 1; off >>= 1)
#pragma unroll
            for (int r = 0; r < 4; ++r)
                rmax[r] = fmaxf(rmax[r], __shfl_xor(rmax[r], off));
        float sc[4];
#pragma unroll
        for (int r = 0; r < 4; ++r) {
            const float nm = fmaxf(m[r], rmax[r]);
            sc[r] = EXP2F(m[r] - nm);        // first tile: exp2(-inf)=0
            m[r]  = nm;
        }
        float rs[4] = {0.f, 0.f, 0.f, 0.f};
#pragma unroll
        for (int n = 0; n < 4; ++n)
#pragma unroll
        for (int r = 0; r < 4; ++r) {
            sa[n][r] = EXP2F(sa[n][r] - m[r]);
            rs[r] += sa[n][r];
        }
#pragma unroll
        for (int off = 8; off >= 1; off >>= 1)
#pragma unroll
            for (int r = 0; r < 4; ++r)
                rs[r] += __shfl_xor(rs[r], off);
#pragma unroll
        for (int r = 0; r < 4; ++r) lsum[r] = lsum[r] * sc[r] + rs[r];
#pragma unroll
        for (int n = 0; n < 4; ++n)
#pragma unroll
        for (int r = 0; r < 4; ++r) o[n][r] *= sc[r];

        // ---- P round-trip in K_lds[nxt] (wave-local rows; same-wave DS
        //      order makes the later WRITE_K to these rows safe) ----
#pragma unroll
        for (int n = 0; n < 4; ++n)
#pragma unroll
        for (int r = 0; r < 4; ++r) {
            const int prow = lg*4 + r;
            K_lds[nxt][(w*16 + prow)*64 + ((n*16 + lr) ^ ((prow & 7) * 8))] = bf16u(sa[n][r]);
        }
        const int fp = (lr & 7) * 8;
        const short8 pa0 = *(const short8*)&K_lds[nxt][(w*16 + lr)*64 + ((lg*8)      ^ fp)];
        const short8 pa1 = *(const short8*)&K_lds[nxt][(w*16 + lr)*64 + ((32 + lg*8) ^ fp)];

        if (pf) {
            WRITE_K(nxt);        // kra dies here
            LOAD_V(t + 1);       // in flight through PV
        }

        // ---- PV ----
        __builtin_amdgcn_s_setprio(1);
#pragma unroll
        for (int n = 0; n < 4; ++n) {
            const int dv  = n*16 + lr;
            const int fv0 = ((lr & 7) ^ (n*2 + (lr >> 3))) * 8;
            const short8 vf0 = *(const short8*)&VT_lds[cur][dv*64 + ((lg*8)      ^ fv0)];
            const short8 vf1 = *(const short8*)&VT_lds[cur][dv*64 + ((32 + lg*8) ^ fv0)];
            o[n] = __builtin_amdgcn_mfma_f32_16x16x32_bf16(pa0, vf0, o[n], 0, 0, 0);
            o[n] = __builtin_amdgcn_mfma_f32_16x16x32_bf16(pa1, vf1, o[n], 0, 0, 0);
        }
        __builtin_amdgcn_s_setprio(0);

        if (pf) WRITE_V(nxt);    // vra dies here
        __syncthreads();         // one barrier per tile
    }

    // ---- epilogue ----
    float inv[4];
#pragma unroll
    for (int r = 0; r < 4; ++r) inv[r] = 1.0f / lsum[r];
#pragma unroll
    for (int n = 0; n < 4; ++n)
#pragma unroll
    for (int r = 0; r < 4; ++r) {
        const int q = qc*64 + w*16 + lg*4 + r;
        Ob[(size_t)q * 64 + n*16 + lr] = o[n][r] * inv[r];
    }
#undef LOAD_K
#undef LOAD_V
#undef WRITE_K
#undef WRITE_V
}

extern "C" void kernel_launch(void* const* d_in, const int* in_sizes, int n_in,
                              void* d_out, int out_size, void* d_ws, size_t ws_size,
                              hipStream_t stream) {
    (void)in_sizes; (void)n_in; (void)d_ws; (void)ws_size; (void)out_size;
    const float* Q  = (const float*)d_in[0];
    const float* K  = (const float*)d_in[1];
    const float* V  = (const float*)d_in[2];
    const int*   vl = (const int*)d_in[3];
    float* O = (float*)d_out;
    attn_fwd<<<dim3(1024), dim3(256), 0, stream>>>(Q, K, V, vl, O);
}

// Round 5
// 65.655 us; speedup vs baseline: 1.2026x; 1.1600x over previous
//
#include <hip/hip_runtime.h>
#include <hip/hip_bf16.h>

#define NEG_BIG -1000000.0f

typedef __attribute__((ext_vector_type(8))) short short8;
typedef __attribute__((ext_vector_type(4))) float floatx4;

#if __has_builtin(__builtin_amdgcn_exp2f)
#define EXP2F(x) __builtin_amdgcn_exp2f(x)
#else
#define EXP2F(x) exp2f(x)
#endif

static __device__ __forceinline__ unsigned short bf16u(float f) {
    union { __hip_bfloat16 h; unsigned short u; } c;
    c.h = __float2bfloat16(f);
    return c.u;
}

static __device__ __forceinline__ short8 pack8(float4 a, float4 b) {
    union { short8 s; __hip_bfloat162 h[4]; } u;
    u.h[0] = __float22bfloat162_rn(make_float2(a.x, a.y));
    u.h[1] = __float22bfloat162_rn(make_float2(a.z, a.w));
    u.h[2] = __float22bfloat162_rn(make_float2(b.x, b.y));
    u.h[3] = __float22bfloat162_rn(make_float2(b.z, b.w));
    return u.s;
}

// SPLIT=true : grid 2048 = (batch 64) x (kchunk 2) x (qchunk 16); each block
//   handles keys [chunk*512, min(kmax, chunk*512+512)). Sites with kmax<=512
//   write output directly; others write (o_unnorm, m, l) partials to ws and a
//   merge kernel combines the two chunks.
// SPLIT=false: grid 1024, full key range, direct write (fallback if ws small).
// Block: 256 thr = 4 waves, 64 q-rows. KV tile 64, double-buffered 32 KB LDS,
// one barrier per tile, P aliased into K prefetch buffer (per-wave rows),
// exp2-domain online softmax. launch_bounds(256,3): 170-reg cap (r3/r4's
// (256,4)=128-cap spilled ~26 MB/dispatch to scratch).
template<bool SPLIT>
__global__ __launch_bounds__(256, 3)
void attn_fwd(const float* __restrict__ Q, const float* __restrict__ K,
              const float* __restrict__ V, const int* __restrict__ vlen,
              float* __restrict__ out, float* __restrict__ ws)
{
    // K_lds: elem (row,col) at row*64 + (col ^ ((row&7)*8))
    __shared__ __attribute__((aligned(16))) unsigned short K_lds[2][4096];
    // VT_lds: elem (dv,k) at dv*64 + (k ^ (((dv&7) ^ (dv>>3)) * 8))
    __shared__ __attribute__((aligned(16))) unsigned short VT_lds[2][4096];

    const int bid = blockIdx.x;
    int b, qc, chunk;
    if (SPLIT) {
        const int orig = (bid & 7) * 256 + (bid >> 3);  // bijective (2048%8==0)
        b = orig >> 5; chunk = (orig >> 4) & 1; qc = orig & 15;
    } else {
        const int orig = (bid & 7) * 128 + (bid >> 3);  // bijective (1024%8==0)
        b = orig >> 4; chunk = 0; qc = orig & 15;
    }

    const int valid = vlen[b];
    const int kmax  = (valid == 0) ? 1024 : valid;   // all-masked -> uniform
    const int ntile = (kmax + 63) >> 6;
    const int tstart = SPLIT ? chunk * 8 : 0;
    const int tend   = SPLIT ? min(ntile, tstart + 8) : ntile;
    if (SPLIT && tstart >= tend) return;             // empty chunk

    const int tid = threadIdx.x;
    const int l   = tid & 63;
    const int w   = tid >> 6;
    const int lr  = l & 15;
    const int lg  = l >> 4;

    const float* Qb = Q + (size_t)b * 65536;
    const float* Kb = K + (size_t)b * 65536;
    const float* Vb = V + (size_t)b * 65536;

    // Q fragments, pre-scaled by log2(e)/sqrt(64)
    const float qscale = 0.18033688011112042f;
    short8 qf[2];
#pragma unroll
    for (int c = 0; c < 2; ++c) {
        const float* p = Qb + (size_t)(qc*64 + w*16 + lr) * 64 + c*32 + lg*8;
        float4 a = *(const float4*)p, bb = *(const float4*)(p + 4);
        a.x *= qscale; a.y *= qscale; a.z *= qscale; a.w *= qscale;
        bb.x *= qscale; bb.y *= qscale; bb.z *= qscale; bb.w *= qscale;
        qf[c] = pack8(a, bb);
    }

    floatx4 o[4];
    float m[4], lsum[4];
#pragma unroll
    for (int n = 0; n < 4; ++n) o[n] = (floatx4){0.f, 0.f, 0.f, 0.f};
#pragma unroll
    for (int r = 0; r < 4; ++r) { m[r] = -INFINITY; lsum[r] = 0.f; }

    // per-wave staging: wave w stages tile rows [w*16, w*16+16)
    const int row   = w * 16 + (l >> 2);  // 0..63
    const int cbase = (l & 3) * 16;       // col quarter (floats)

    float4 kra[4], vra[4];

#define LOAD_K(T) do {                                                      \
    const float* pk = Kb + (size_t)((T)*64 + row) * 64 + cbase;             \
    kra[0] = *(const float4*)pk;       kra[1] = *(const float4*)(pk + 4);   \
    kra[2] = *(const float4*)(pk + 8); kra[3] = *(const float4*)(pk + 12);  \
    } while (0)

#define LOAD_V(T) do {                                                      \
    const float* pv = Vb + (size_t)((T)*64 + row) * 64 + cbase;             \
    vra[0] = *(const float4*)pv;       vra[1] = *(const float4*)(pv + 4);   \
    vra[2] = *(const float4*)(pv + 8); vra[3] = *(const float4*)(pv + 12);  \
    } while (0)

#define WRITE_K(B) do {                                                     \
    const int _fk = (row & 7) * 8;                                          \
    *(short8*)&K_lds[B][row*64 + (cbase ^ _fk)]       = pack8(kra[0], kra[1]); \
    *(short8*)&K_lds[B][row*64 + ((cbase + 8) ^ _fk)] = pack8(kra[2], kra[3]); \
    } while (0)

#define WRITE_V(B) do {                                                     \
    _Pragma("unroll")                                                       \
    for (int j = 0; j < 16; ++j) {                                          \
        const int dv = cbase + j;                                           \
        const int fv = ((dv & 7) ^ (dv >> 3)) * 8;                          \
        VT_lds[B][dv*64 + (row ^ fv)] = bf16u(((const float*)&vra[j>>2])[j&3]); \
    } } while (0)

    LOAD_K(tstart);
    LOAD_V(tstart);
    WRITE_K(0);
    WRITE_V(0);
    __syncthreads();

    for (int t = tstart; t < tend; ++t) {
        const int cur = (t - tstart) & 1;
        const int nxt = cur ^ 1;
        const int k0  = t * 64;
        const bool pf = (t + 1 < tend);

        if (pf) LOAD_K(t + 1);   // in flight through QK^T + softmax

        // ---- QK^T: S[16q x 64k]; lane holds q=lg*4+r, k=n*16+lr ----
        floatx4 sa[4];
        __builtin_amdgcn_s_setprio(1);
#pragma unroll
        for (int n = 0; n < 4; ++n) {
            const int kr = n*16 + lr;
            const int fk = (lr & 7) * 8;
            const short8 kf0 = *(const short8*)&K_lds[cur][kr*64 + ((lg*8)      ^ fk)];
            const short8 kf1 = *(const short8*)&K_lds[cur][kr*64 + ((32 + lg*8) ^ fk)];
            sa[n] = (floatx4){0.f, 0.f, 0.f, 0.f};
            sa[n] = __builtin_amdgcn_mfma_f32_16x16x32_bf16(qf[0], kf0, sa[n], 0, 0, 0);
            sa[n] = __builtin_amdgcn_mfma_f32_16x16x32_bf16(qf[1], kf1, sa[n], 0, 0, 0);
        }
        __builtin_amdgcn_s_setprio(0);

        if ((k0 + 64) > valid) {
#pragma unroll
            for (int n = 0; n < 4; ++n) {
                const bool msk = (k0 + n*16 + lr) >= valid;
#pragma unroll
                for (int r = 0; r < 4; ++r) sa[n][r] = msk ? NEG_BIG : sa[n][r];
            }
        }

        // ---- online softmax, exp2 domain; sa becomes P in place ----
        float rmax[4];
#pragma unroll
        for (int r = 0; r < 4; ++r)
            rmax[r] = fmaxf(fmaxf(sa[0][r], sa[1][r]), fmaxf(sa[2][r], sa[3][r]));
#pragma unroll
        for (int off = 8; off >= 1; off >>= 1)
#pragma unroll
            for (int r = 0; r < 4; ++r)
                rmax[r] = fmaxf(rmax[r], __shfl_xor(rmax[r], off));
        float sc[4];
#pragma unroll
        for (int r = 0; r < 4; ++r) {
            const float nm = fmaxf(m[r], rmax[r]);
            sc[r] = EXP2F(m[r] - nm);        // first tile: exp2(-inf)=0
            m[r]  = nm;
        }
        float rs[4] = {0.f, 0.f, 0.f, 0.f};
#pragma unroll
        for (int n = 0; n < 4; ++n)
#pragma unroll
        for (int r = 0; r < 4; ++r) {
            sa[n][r] = EXP2F(sa[n][r] - m[r]);
            rs[r] += sa[n][r];
        }
#pragma unroll
        for (int off = 8; off >= 1; off >>= 1)
#pragma unroll
            for (int r = 0; r < 4; ++r)
                rs[r] += __shfl_xor(rs[r], off);
#pragma unroll
        for (int r = 0; r < 4; ++r) lsum[r] = lsum[r] * sc[r] + rs[r];
#pragma unroll
        for (int n = 0; n < 4; ++n)
#pragma unroll
        for (int r = 0; r < 4; ++r) o[n][r] *= sc[r];

        // ---- P round-trip in K_lds[nxt] (wave-local rows; same-wave DS
        //      order makes the later WRITE_K to these rows safe) ----
#pragma unroll
        for (int n = 0; n < 4; ++n)
#pragma unroll
        for (int r = 0; r < 4; ++r) {
            const int prow = lg*4 + r;
            K_lds[nxt][(w*16 + prow)*64 + ((n*16 + lr) ^ ((prow & 7) * 8))] = bf16u(sa[n][r]);
        }
        const int fp = (lr & 7) * 8;
        const short8 pa0 = *(const short8*)&K_lds[nxt][(w*16 + lr)*64 + ((lg*8)      ^ fp)];
        const short8 pa1 = *(const short8*)&K_lds[nxt][(w*16 + lr)*64 + ((32 + lg*8) ^ fp)];

        if (pf) {
            WRITE_K(nxt);        // kra dies here
            LOAD_V(t + 1);       // in flight through PV
        }

        // ---- PV ----
        __builtin_amdgcn_s_setprio(1);
#pragma unroll
        for (int n = 0; n < 4; ++n) {
            const int dv  = n*16 + lr;
            const int fv0 = ((lr & 7) ^ (n*2 + (lr >> 3))) * 8;
            const short8 vf0 = *(const short8*)&VT_lds[cur][dv*64 + ((lg*8)      ^ fv0)];
            const short8 vf1 = *(const short8*)&VT_lds[cur][dv*64 + ((32 + lg*8) ^ fv0)];
            o[n] = __builtin_amdgcn_mfma_f32_16x16x32_bf16(pa0, vf0, o[n], 0, 0, 0);
            o[n] = __builtin_amdgcn_mfma_f32_16x16x32_bf16(pa1, vf1, o[n], 0, 0, 0);
        }
        __builtin_amdgcn_s_setprio(0);

        if (pf) WRITE_V(nxt);    // vra dies here
        __syncthreads();         // one barrier per tile
    }

    // ---- epilogue ----
    if (!SPLIT || ntile <= 8) {
        // single chunk covers the whole key range: normalized direct write
        float* Ob = out + (size_t)b * 65536;
        float inv[4];
#pragma unroll
        for (int r = 0; r < 4; ++r) inv[r] = 1.0f / lsum[r];
#pragma unroll
        for (int n = 0; n < 4; ++n)
#pragma unroll
        for (int r = 0; r < 4; ++r) {
            const int q = qc*64 + w*16 + lg*4 + r;
            Ob[(size_t)q * 64 + n*16 + lr] = o[n][r] * inv[r];
        }
    } else {
        // partial: unnormalized o + per-row m, l
        float* wsb = ws + ((size_t)((b*16 + qc)*2 + chunk)) * 4224;
#pragma unroll
        for (int n = 0; n < 4; ++n)
#pragma unroll
        for (int r = 0; r < 4; ++r) {
            const int q_loc = w*16 + lg*4 + r;
            wsb[q_loc*64 + n*16 + lr] = o[n][r];
        }
        if (lr == 0) {
#pragma unroll
            for (int r = 0; r < 4; ++r) {
                const int q_loc = w*16 + lg*4 + r;
                wsb[4096 + q_loc] = m[r];
                wsb[4160 + q_loc] = lsum[r];
            }
        }
    }
#undef LOAD_K
#undef LOAD_V
#undef WRITE_K
#undef WRITE_V
}

// merge the two k-chunk partials for sites with kmax > 512
__global__ __launch_bounds__(256)
void attn_merge(const int* __restrict__ vlen, const float* __restrict__ ws,
                float* __restrict__ out)
{
    const int site = blockIdx.x;       // b*16 + qc
    const int b    = site >> 4;
    const int qc   = site & 15;
    const int valid = vlen[b];
    const int kmax  = (valid == 0) ? 1024 : valid;
    if (kmax <= 512) return;           // chunk0 wrote output directly

    const int tid   = threadIdx.x;
    const int q_loc = tid >> 2;        // 0..63
    const int dg    = (tid & 3) * 16;  // 0,16,32,48

    const float* w0 = ws + (size_t)site * 2 * 4224;
    const float* w1 = w0 + 4224;
    const float m0 = w0[4096 + q_loc], l0 = w0[4160 + q_loc];
    const float m1 = w1[4096 + q_loc], l1 = w1[4160 + q_loc];
    const float M  = fmaxf(m0, m1);
    const float a0 = EXP2F(m0 - M), a1 = EXP2F(m1 - M);
    const float inv = 1.0f / (l0 * a0 + l1 * a1);

    const float4* o0 = (const float4*)(w0 + q_loc*64 + dg);
    const float4* o1 = (const float4*)(w1 + q_loc*64 + dg);
    float4* dst = (float4*)(out + ((size_t)(b*1024 + qc*64 + q_loc)) * 64 + dg);
#pragma unroll
    for (int i = 0; i < 4; ++i) {
        const float4 p = o0[i], q = o1[i];
        float4 r;
        r.x = (p.x * a0 + q.x * a1) * inv;
        r.y = (p.y * a0 + q.y * a1) * inv;
        r.z = (p.z * a0 + q.z * a1) * inv;
        r.w = (p.w * a0 + q.w * a1) * inv;
        dst[i] = r;
    }
}

extern "C" void kernel_launch(void* const* d_in, const int* in_sizes, int n_in,
                              void* d_out, int out_size, void* d_ws, size_t ws_size,
                              hipStream_t stream) {
    (void)in_sizes; (void)n_in; (void)out_size;
    const float* Q  = (const float*)d_in[0];
    const float* K  = (const float*)d_in[1];
    const float* V  = (const float*)d_in[2];
    const int*   vl = (const int*)d_in[3];
    float* O  = (float*)d_out;
    float* WS = (float*)d_ws;

    const size_t need = (size_t)1024 * 2 * 4224 * sizeof(float);  // 34.6 MB
    if (ws_size >= need) {
        attn_fwd<true><<<dim3(2048), dim3(256), 0, stream>>>(Q, K, V, vl, O, WS);
        attn_merge<<<dim3(1024), dim3(256), 0, stream>>>(vl, WS, O);
    } else {
        attn_fwd<false><<<dim3(1024), dim3(256), 0, stream>>>(Q, K, V, vl, O, WS);
    }
}

// Round 6
// 45.293 us; speedup vs baseline: 1.7432x; 1.4496x over previous
//
#include <hip/hip_runtime.h>
#include <hip/hip_bf16.h>

#define NEG_BIG -1000000.0f

typedef __attribute__((ext_vector_type(8))) short short8;
typedef __attribute__((ext_vector_type(4))) short short4v;
typedef __attribute__((ext_vector_type(4))) float floatx4;

#if __has_builtin(__builtin_amdgcn_exp2f)
#define EXP2F(x) __builtin_amdgcn_exp2f(x)
#else
#define EXP2F(x) exp2f(x)
#endif

// K=16 bf16 MFMA: A[row=lane&15][k=4*(lane>>4)+j], B[k][col=lane&15],
// D col=lane&15, row=4*(lane>>4)+reg  (gfx90a-lineage shape, kept on gfx950)
#if __has_builtin(__builtin_amdgcn_mfma_f32_16x16x16bf16_1k)
#define MFMA16(a, b, c) __builtin_amdgcn_mfma_f32_16x16x16bf16_1k(a, b, c, 0, 0, 0)
#else
static __device__ __forceinline__ floatx4 MFMA16_fn(short4v a, short4v b, floatx4 c) {
    floatx4 d;
    asm("v_mfma_f32_16x16x16_bf16 %0, %1, %2, %3\n\ts_nop 4"
        : "=v"(d) : "v"(a), "v"(b), "v"(c));
    return d;
}
#define MFMA16(a, b, c) MFMA16_fn(a, b, c)
#endif

static __device__ __forceinline__ unsigned short bf16u(float f) {
    union { __hip_bfloat16 h; unsigned short u; } c;
    c.h = __float2bfloat16(f);
    return c.u;
}

static __device__ __forceinline__ short8 pack8(float4 a, float4 b) {
    union { short8 s; __hip_bfloat162 h[4]; } u;
    u.h[0] = __float22bfloat162_rn(make_float2(a.x, a.y));
    u.h[1] = __float22bfloat162_rn(make_float2(a.z, a.w));
    u.h[2] = __float22bfloat162_rn(make_float2(b.x, b.y));
    u.h[3] = __float22bfloat162_rn(make_float2(b.z, b.w));
    return u.s;
}

// Block: 256 thr = 4 waves, 64 q-rows (wave owns one 16-row tile).
// Grid: 1024 blocks, XCD-swizzled. KV tile 64, double-buffered 32 KB LDS,
// one barrier per tile.
// SWAPPED QK^T: sa[n] = mfma(K,Q) -> lane holds S^T[k=n*16+lg*4+r][q=lr]:
//   softmax is lane-local (16 vals) + 2 shfl hops; m/lsum scalar per lane.
//   P converts in-register to the EXACT A-fragment of 16x16x16 bf16 MFMA
//   (k=lg*4+j) -> PV needs no P LDS round-trip and no lane redistribution.
__global__ __launch_bounds__(256, 3)
void attn_fwd(const float* __restrict__ Q, const float* __restrict__ K,
              const float* __restrict__ V, const int* __restrict__ vlen,
              float* __restrict__ out)
{
    // K_lds: elem (row,col) at row*64 + (col ^ ((row&7)*8))
    __shared__ __attribute__((aligned(16))) unsigned short K_lds[2][4096];
    // VT_lds: elem (dv,k) at dv*64 + (k ^ (((dv&7) ^ (dv>>3)) * 8))
    __shared__ __attribute__((aligned(16))) unsigned short VT_lds[2][4096];

    const int bid  = blockIdx.x;
    const int orig = (bid & 7) * 128 + (bid >> 3);  // bijective (1024%8==0)
    const int b    = orig >> 4;
    const int qc   = orig & 15;

    const int tid = threadIdx.x;
    const int l   = tid & 63;
    const int w   = tid >> 6;
    const int lr  = l & 15;
    const int lg  = l >> 4;

    const float* Qb = Q + (size_t)b * 65536;
    const float* Kb = K + (size_t)b * 65536;
    const float* Vb = V + (size_t)b * 65536;

    const int valid = vlen[b];
    const int kmax  = (valid == 0) ? 1024 : valid;   // all-masked -> uniform
    const int ntile = (kmax + 63) >> 6;

    // Q fragments (B-operand: col=q=lr, d=lg*8+j), pre-scaled log2(e)/8
    const float qscale = 0.18033688011112042f;
    short8 qf[2];
#pragma unroll
    for (int c = 0; c < 2; ++c) {
        const float* p = Qb + (size_t)(qc*64 + w*16 + lr) * 64 + c*32 + lg*8;
        float4 a = *(const float4*)p, bb = *(const float4*)(p + 4);
        a.x *= qscale; a.y *= qscale; a.z *= qscale; a.w *= qscale;
        bb.x *= qscale; bb.y *= qscale; bb.z *= qscale; bb.w *= qscale;
        qf[c] = pack8(a, bb);
    }

    floatx4 o[4];
#pragma unroll
    for (int n = 0; n < 4; ++n) o[n] = (floatx4){0.f, 0.f, 0.f, 0.f};
    float m = -INFINITY, lsum = 0.f;     // scalar state for q-row lr

    // per-wave staging: wave w stages tile rows [w*16, w*16+16)
    const int row   = w * 16 + (l >> 2);  // 0..63
    const int cbase = (l & 3) * 16;       // col quarter (floats)

    float4 kra[4], vra[4];

#define LOAD_K(T) do {                                                      \
    const float* pk = Kb + (size_t)((T)*64 + row) * 64 + cbase;             \
    kra[0] = *(const float4*)pk;       kra[1] = *(const float4*)(pk + 4);   \
    kra[2] = *(const float4*)(pk + 8); kra[3] = *(const float4*)(pk + 12);  \
    } while (0)

#define LOAD_V(T) do {                                                      \
    const float* pv = Vb + (size_t)((T)*64 + row) * 64 + cbase;             \
    vra[0] = *(const float4*)pv;       vra[1] = *(const float4*)(pv + 4);   \
    vra[2] = *(const float4*)(pv + 8); vra[3] = *(const float4*)(pv + 12);  \
    } while (0)

#define WRITE_K(B) do {                                                     \
    const int _fk = (row & 7) * 8;                                          \
    *(short8*)&K_lds[B][row*64 + (cbase ^ _fk)]       = pack8(kra[0], kra[1]); \
    *(short8*)&K_lds[B][row*64 + ((cbase + 8) ^ _fk)] = pack8(kra[2], kra[3]); \
    } while (0)

#define WRITE_V(B) do {                                                     \
    _Pragma("unroll")                                                       \
    for (int j = 0; j < 16; ++j) {                                          \
        const int dv = cbase + j;                                           \
        const int fv = ((dv & 7) ^ (dv >> 3)) * 8;                          \
        VT_lds[B][dv*64 + (row ^ fv)] = bf16u(((const float*)&vra[j>>2])[j&3]); \
    } } while (0)

    LOAD_K(0);
    LOAD_V(0);
    WRITE_K(0);
    WRITE_V(0);
    __syncthreads();

    for (int t = 0; t < ntile; ++t) {
        const int cur = t & 1;
        const int nxt = cur ^ 1;
        const int k0  = t * 64;
        const bool pf = (t + 1 < ntile);

        if (pf) { LOAD_K(t + 1); LOAD_V(t + 1); }   // max load->use distance

        // ---- swapped QK^T: sa[n][r] = S[k=k0+n*16+lg*4+r][q=lr] ----
        floatx4 sa[4];
        __builtin_amdgcn_s_setprio(1);
#pragma unroll
        for (int n = 0; n < 4; ++n) {
            const int kr = n*16 + lr;
            const int fk = (lr & 7) * 8;
            const short8 kf0 = *(const short8*)&K_lds[cur][kr*64 + ((lg*8)      ^ fk)];
            const short8 kf1 = *(const short8*)&K_lds[cur][kr*64 + ((32 + lg*8) ^ fk)];
            sa[n] = (floatx4){0.f, 0.f, 0.f, 0.f};
            sa[n] = __builtin_amdgcn_mfma_f32_16x16x32_bf16(kf0, qf[0], sa[n], 0, 0, 0);
            sa[n] = __builtin_amdgcn_mfma_f32_16x16x32_bf16(kf1, qf[1], sa[n], 0, 0, 0);
        }
        __builtin_amdgcn_s_setprio(0);

        if ((k0 + 64) > valid) {
            const int kb = k0 + lg*4;
#pragma unroll
            for (int n = 0; n < 4; ++n)
#pragma unroll
            for (int r = 0; r < 4; ++r)
                sa[n][r] = (kb + n*16 + r >= valid) ? NEG_BIG : sa[n][r];
        }

        // ---- lane-local online softmax (exp2 domain), q-row = lr ----
        float rmax = fmaxf(
            fmaxf(fmaxf(fmaxf(sa[0][0], sa[0][1]), fmaxf(sa[0][2], sa[0][3])),
                  fmaxf(fmaxf(sa[1][0], sa[1][1]), fmaxf(sa[1][2], sa[1][3]))),
            fmaxf(fmaxf(fmaxf(sa[2][0], sa[2][1]), fmaxf(sa[2][2], sa[2][3])),
                  fmaxf(fmaxf(sa[3][0], sa[3][1]), fmaxf(sa[3][2], sa[3][3]))));
        rmax = fmaxf(rmax, __shfl_xor(rmax, 16));
        rmax = fmaxf(rmax, __shfl_xor(rmax, 32));

        const float nm = fmaxf(m, rmax);
        const float sc = EXP2F(m - nm);          // first tile: exp2(-inf)=0
        m = nm;

        float rs = 0.f;
#pragma unroll
        for (int n = 0; n < 4; ++n)
#pragma unroll
        for (int r = 0; r < 4; ++r) {
            sa[n][r] = EXP2F(sa[n][r] - m);
            rs += sa[n][r];
        }
        rs += __shfl_xor(rs, 16);
        rs += __shfl_xor(rs, 32);
        lsum = lsum * sc + rs;

        // broadcast rescale factor for accumulator rows q=lg*4+r
        float sc_r[4];
#pragma unroll
        for (int r = 0; r < 4; ++r) sc_r[r] = __shfl(sc, lg*4 + r);
#pragma unroll
        for (int n = 0; n < 4; ++n)
#pragma unroll
        for (int r = 0; r < 4; ++r) o[n][r] *= sc_r[r];

        // ---- P in-register -> A-fragments for 16x16x16 MFMA ----
        short4v pk[4];
#pragma unroll
        for (int n = 0; n < 4; ++n) {
            union { short4v s; __hip_bfloat162 h[2]; } u;
            u.h[0] = __float22bfloat162_rn(make_float2(sa[n][0], sa[n][1]));
            u.h[1] = __float22bfloat162_rn(make_float2(sa[n][2], sa[n][3]));
            pk[n] = u.s;
        }

        if (pf) WRITE_K(nxt);    // kra dies here

        // ---- PV: o[n2] += P[q][k] * V[k][dv], 16x16x16 per (kc,n2) ----
        __builtin_amdgcn_s_setprio(1);
#pragma unroll
        for (int kc = 0; kc < 4; ++kc) {
#pragma unroll
            for (int n2 = 0; n2 < 4; ++n2) {
                const int dv = n2*16 + lr;
                const int fv = ((dv & 7) ^ (dv >> 3)) * 8;
                const short4v vf = *(const short4v*)&VT_lds[cur][dv*64 + ((kc*16 + lg*4) ^ fv)];
                o[n2] = MFMA16(pk[kc], vf, o[n2]);
            }
        }
        __builtin_amdgcn_s_setprio(0);

        if (pf) WRITE_V(nxt);    // vra dies here
        __syncthreads();         // one barrier per tile
    }

    // ---- epilogue: normalize and store (coalesced) ----
    const float inv = 1.0f / lsum;
    float inv_r[4];
#pragma unroll
    for (int r = 0; r < 4; ++r) inv_r[r] = __shfl(inv, lg*4 + r);

    float* Ob = out + (size_t)b * 65536;
#pragma unroll
    for (int n = 0; n < 4; ++n)
#pragma unroll
    for (int r = 0; r < 4; ++r) {
        const int q = qc*64 + w*16 + lg*4 + r;
        Ob[(size_t)q * 64 + n*16 + lr] = o[n][r] * inv_r[r];
    }
#undef LOAD_K
#undef LOAD_V
#undef WRITE_K
#undef WRITE_V
}

extern "C" void kernel_launch(void* const* d_in, const int* in_sizes, int n_in,
                              void* d_out, int out_size, void* d_ws, size_t ws_size,
                              hipStream_t stream) {
    (void)in_sizes; (void)n_in; (void)d_ws; (void)ws_size; (void)out_size;
    const float* Q  = (const float*)d_in[0];
    const float* K  = (const float*)d_in[1];
    const float* V  = (const float*)d_in[2];
    const int*   vl = (const int*)d_in[3];
    float* O = (float*)d_out;
    attn_fwd<<<dim3(1024), dim3(256), 0, stream>>>(Q, K, V, vl, O);
}